// Round 5
// baseline (641.484 us; speedup 1.0000x reference)
//
#include <hip/hip_runtime.h>

// GRU: B=4096, T=512, I=32, H=64. One WG per 16-batch tile.
// R6: 8 waves/WG (512 thr) = 2 waves/SIMD. (Round 4: verbatim resubmit —
// Round 3 proposal never ran, GPU acquisition timeout.)
// R5b evidence: occupancy 11.7% (1 wave/SIMD), VALUBusy 39.5%, MfmaUtil
// 13.3% -> ~550 cyc/step of exposed latency with no co-resident wave to
// hide it. Grid is fixed at 256 WGs (4096/16 batches), so occupancy
// comes from splitting each R5b wave into a PAIR: both waves compute
// the same 9 MFMAs (redundant; MFMA pipe was 13% busy) but each runs
// the trans-heavy epilogue for only 2 of the 4 C-rows (r={0,1} vs
// {2,3}, wave-uniform branch so all vector indices are compile-time).
// Per-SIMD VALU issue unchanged (~450 cyc/step, split not duplicated);
// exposed latency hidden by the second wave (m114 MFMA/VALU co-sched).
// Register seq-queue shrunk 8->4 slots/chunk (64 VGPR) so 2 waves/SIMD
// fit under the 256-VGPR cap; prefetch distance 4 steps (~2000 cyc)
// still >> ~900 cyc HBM latency.
// Carries R5b's compiler-proof load pipeline: untracked inline-asm
// global_load_dwordx4 bursts, data-dep vmcnt(0) drains, raw
// lgkmcnt(0)+s_barrier (no vmcnt drain at barriers).

#define TSTEPS 512
#define IDIM 32
#define HDIM 64

typedef __bf16 bf16x8 __attribute__((ext_vector_type(8)));
typedef __bf16 bf16x2 __attribute__((ext_vector_type(2)));
typedef float f32x4 __attribute__((ext_vector_type(4)));
typedef float f32x2 __attribute__((ext_vector_type(2)));

#define NLOG2E -1.4426950408889634f
#define TWOLOG2E 2.8853900817779268f

// Two untracked 16B loads (one timestep slice per lane = 8 floats =
// 2x float4) from base+literal offsets.
#define LOADPAIR(dst0, dst1, ptr, off)                                     \
    asm volatile("global_load_dwordx4 %0, %2, off offset:%c3\n\t"          \
                 "global_load_dwordx4 %1, %2, off offset:%c4"              \
        : "=&v"(dst0), "=&v"(dst1)                                         \
        : "v"(ptr), "i"(off), "i"((off) + 16));

// Issue one 4-timestep chunk (512 B contiguous per lane) as 8 untracked
// global_load_dwordx4. Stride between timesteps = IDIM*4 = 128 B.
#define ISSUE_CHUNK(qq, baseT) do {                                        \
    const float* _p = seqRow + (size_t)(baseT) * IDIM;                     \
    LOADPAIR(qq[0][0], qq[0][1], _p, 0)                                    \
    LOADPAIR(qq[1][0], qq[1][1], _p, 128)                                  \
    LOADPAIR(qq[2][0], qq[2][1], _p, 256)                                  \
    LOADPAIR(qq[3][0], qq[3][1], _p, 384)                                  \
} while (0)

// Drain the untracked loads; tie all destinations so no consumer can be
// scheduled above the wait (true data dependence).
#define WAITDEP(qq)                                                        \
    asm volatile("s_waitcnt vmcnt(0)"                                      \
        : "+v"(qq[0][0]), "+v"(qq[0][1]), "+v"(qq[1][0]), "+v"(qq[1][1]), \
          "+v"(qq[2][0]), "+v"(qq[2][1]), "+v"(qq[3][0]), "+v"(qq[3][1]))

// Raw barrier: LDS drained manually; NO vmcnt drain. "memory" clobber
// pins DS ops (esp. the hOut ds_write) on the correct side.
#define WG_BARRIER() do {                                                  \
    asm volatile("s_waitcnt lgkmcnt(0)" ::: "memory");                     \
    __builtin_amdgcn_s_barrier();                                          \
} while (0)

// Epilogue for two C-rows R0,R1 (compile-time indices); updates
// h[0],h[1] and writes bf16x2 to hPtr.
#define EPILOG(R0, R1, hPtr) do {                                          \
    bf16x2 hOut;                                                           \
    {                                                                      \
        const float rg = __builtin_amdgcn_rcpf(1.0f + __builtin_amdgcn_exp2f(accR[R0])); \
        const float zg = __builtin_amdgcn_rcpf(1.0f + __builtin_amdgcn_exp2f(accZ[R0])); \
        const float v  = accXN[R0] + rg * accHN[R0];                       \
        const float u  = __builtin_amdgcn_exp2f(TWOLOG2E * v);             \
        const float ng = 1.0f - 2.0f * __builtin_amdgcn_rcpf(1.0f + u);    \
        h[0] = ng + zg * (h[0] - ng);                                      \
        hOut[0] = (__bf16)h[0];                                            \
    }                                                                      \
    {                                                                      \
        const float rg = __builtin_amdgcn_rcpf(1.0f + __builtin_amdgcn_exp2f(accR[R1])); \
        const float zg = __builtin_amdgcn_rcpf(1.0f + __builtin_amdgcn_exp2f(accZ[R1])); \
        const float v  = accXN[R1] + rg * accHN[R1];                       \
        const float u  = __builtin_amdgcn_exp2f(TWOLOG2E * v);             \
        const float ng = 1.0f - 2.0f * __builtin_amdgcn_rcpf(1.0f + u);    \
        h[1] = ng + zg * (h[1] - ng);                                      \
        hOut[1] = (__bf16)h[1];                                            \
    }                                                                      \
    *(bf16x2*)(hPtr) = hOut;                                               \
} while (0)

__global__ __launch_bounds__(512, 2) void gru_fused_kernel(
    const float* __restrict__ seq, const float* __restrict__ W_ih,
    const float* __restrict__ W_hh, const float* __restrict__ b_ih,
    const float* __restrict__ b_hh, float* __restrict__ out)
{
    __shared__ __bf16 hB[2][16][72];  // h^T double-buffered; 144 B row stride

    const int tid  = threadIdx.x;
    const int w    = tid >> 6;        // 0..7
    const int hw   = w >> 1;          // hidden slice 0..3 (rows hw*16..hw*16+15)
    const int sub  = w & 1;           // epilogue half: 0 -> r{0,1}, 1 -> r{2,3}
    const int lane = tid & 63;
    const int l    = lane & 15;       // batch col
    const int q    = lane >> 4;       // quad
    const int b0   = blockIdx.x * 16;

    for (int i = tid; i < 2 * 16 * 72; i += 512)
        (&hB[0][0][0])[i] = (__bf16)0.0f;

    // ---- A-fragments; r,z gates pre-scaled by -log2e ----
    bf16x8 aH[3][2], aI[3];
    #pragma unroll
    for (int g = 0; g < 3; ++g) {
        const float scl = (g < 2) ? NLOG2E : 1.0f;
        const int row = g * 64 + hw * 16 + l;
        #pragma unroll
        for (int kc = 0; kc < 2; ++kc) {
            const float* p = W_hh + row * HDIM + kc * 32 + q * 8;
            #pragma unroll
            for (int j = 0; j < 8; ++j) aH[g][kc][j] = (__bf16)(scl * p[j]);
        }
        const float* pi = W_ih + row * IDIM + q * 8;
        #pragma unroll
        for (int j = 0; j < 8; ++j) aI[g][j] = (__bf16)(scl * pi[j]);
    }

    // ---- bias C-init vectors at this pair's C/D rows (hidden = hw*16+4q+r) ----
    f32x4 biasR4, biasZ4, biasXN4, biasHN4;
    #pragma unroll
    for (int r = 0; r < 4; ++r) {
        const int g = hw * 16 + 4 * q + r;
        biasR4[r]  = NLOG2E * (b_ih[g]      + b_hh[g]);
        biasZ4[r]  = NLOG2E * (b_ih[64 + g] + b_hh[64 + g]);
        biasXN4[r] = b_ih[128 + g];
        biasHN4[r] = b_hh[128 + g];
    }

    float h[2] = {0.f, 0.f};          // this wave's two h values (r = 2*sub+{0,1})

    const float* seqRow = seq + ((size_t)(b0 + l) * TSTEPS) * IDIM + q * 8;

    // ---- 4-step register queues, loaded ONLY via untracked asm loads.
    // qA = chunk [tc, tc+4), qB = chunk [tc+4, tc+8).
    f32x4 qA[4][2], qB[4][2];
    ISSUE_CHUNK(qA, 0);
    ISSUE_CHUNK(qB, 4);
    WAITDEP(qA);            // vmcnt(0): one-time drain of both chunks
    WAITDEP(qB);            // free (already 0); establishes qB data-dep

    WG_BARRIER();           // hB zero-init visible

    // ---- t=0 x-part (bias-init C) ----
    bf16x8 xb;
    #pragma unroll
    for (int j = 0; j < 4; ++j) {
        xb[j]     = (__bf16)qA[0][0][j];
        xb[4 + j] = (__bf16)qA[0][1][j];
    }
    f32x4 accR  = __builtin_amdgcn_mfma_f32_16x16x32_bf16(aI[0], xb, biasR4, 0, 0, 0);
    f32x4 accZ  = __builtin_amdgcn_mfma_f32_16x16x32_bf16(aI[1], xb, biasZ4, 0, 0, 0);
    f32x4 accXN = __builtin_amdgcn_mfma_f32_16x16x32_bf16(aI[2], xb, biasXN4, 0, 0, 0);

    __bf16* const hWr = &hB[0][0][0] + l * 72 + hw * 16 + 4 * q + 2 * sub;  // + buf*16*72

    for (int tc = 0; tc < TSTEPS; tc += 8) {
        #pragma unroll
        for (int s = 0; s < 8; ++s) {
            const int buf = s & 1;  // tc is a multiple of 8

            // post-barrier critical path: h^T fragments
            bf16x8 hb0 = *(const bf16x8*)&hB[buf][l][q * 8];
            bf16x8 hb1 = *(const bf16x8*)&hB[buf][l][32 + q * 8];

            accR = __builtin_amdgcn_mfma_f32_16x16x32_bf16(aH[0][0], hb0, accR, 0, 0, 0);
            accR = __builtin_amdgcn_mfma_f32_16x16x32_bf16(aH[0][1], hb1, accR, 0, 0, 0);
            accZ = __builtin_amdgcn_mfma_f32_16x16x32_bf16(aH[1][0], hb0, accZ, 0, 0, 0);
            accZ = __builtin_amdgcn_mfma_f32_16x16x32_bf16(aH[1][1], hb1, accZ, 0, 0, 0);
            f32x4 accHN = __builtin_amdgcn_mfma_f32_16x16x32_bf16(aH[2][0], hb0, biasHN4, 0, 0, 0);
            accHN = __builtin_amdgcn_mfma_f32_16x16x32_bf16(aH[2][1], hb1, accHN, 0, 0, 0);

            // epilogue for this wave's 2 C-rows (wave-uniform branch;
            // compile-time vector indices on both sides)
            __bf16* hp = hWr + (buf ^ 1) * (16 * 72);
            if (sub == 0) { EPILOG(0, 1, hp); } else { EPILOG(2, 3, hp); }

            // burst pipeline: drain the chunk first needed NEXT sub-phase
            // (issued 4 steps ago, ~2000 cyc of cover), then issue ahead.
            if (s == 3) {
                WAITDEP(qB);                              // chunk tc+4 ready
                if (tc + 8 < TSTEPS) ISSUE_CHUNK(qA, tc + 8);
            }
            if (s == 7) {
                WAITDEP(qA);                              // chunk tc+8 ready
                if (tc + 12 < TSTEPS) ISSUE_CHUNK(qB, tc + 12);
            }

            // ---- pre-barrier work for t+1 (h-independent): cvt + x-proj MFMAs ----
            // s+1: slot in qA if <4 else qB; at s==7 uses qA[0] (refilled at
            // s==3). Final step of the kernel computes a dead x-proj for
            // t=512 from stale regs — harmless, results unused.
            {
                const int s1 = s + 1;
                const f32x4* x0 = (s1 < 4) ? &qA[s1 & 3][0]
                                           : (s1 < 8) ? &qB[s1 & 3][0]
                                                      : &qA[0][0];
                bf16x8 xb1;
                #pragma unroll
                for (int j = 0; j < 4; ++j) {
                    xb1[j]     = (__bf16)x0[0][j];
                    xb1[4 + j] = (__bf16)x0[1][j];
                }
                accR  = __builtin_amdgcn_mfma_f32_16x16x32_bf16(aI[0], xb1, biasR4, 0, 0, 0);
                accZ  = __builtin_amdgcn_mfma_f32_16x16x32_bf16(aI[1], xb1, biasZ4, 0, 0, 0);
                accXN = __builtin_amdgcn_mfma_f32_16x16x32_bf16(aI[2], xb1, biasXN4, 0, 0, 0);
            }

            WG_BARRIER();
        }
    }

    f32x2 o = {h[0], h[1]};
    *(f32x2*)&out[(size_t)(b0 + l) * HDIM + hw * 16 + 4 * q + 2 * sub] = o;
}

extern "C" void kernel_launch(void* const* d_in, const int* in_sizes, int n_in,
                              void* d_out, int out_size, void* d_ws, size_t ws_size,
                              hipStream_t stream) {
    const float* seq  = (const float*)d_in[0];
    const float* W_ih = (const float*)d_in[1];
    const float* W_hh = (const float*)d_in[2];
    const float* b_ih = (const float*)d_in[3];
    const float* b_hh = (const float*)d_in[4];
    float* out = (float*)d_out;
    gru_fused_kernel<<<256, 512, 0, stream>>>(seq, W_ih, W_hh, b_ih, b_hh, out);
}

// Round 7
// 484.879 us; speedup vs baseline: 1.3230x; 1.3230x over previous
//
#include <hip/hip_runtime.h>

// GRU: B=4096, T=512, I=32, H=64. One WG per 16-batch tile, 4 waves.
// Wave w owns hidden slice [w*16, w*16+16) for all 3 gates.
// hp^T = W_hh * h^T: A = weight rows in registers, B = h^T from LDS.
//
// R7 = R5b (241 us) + merged-rcp epilogue. (Round 6: verbatim resubmit —
// Round 5 proposal hit "container failed twice", same infra failure as
// Round 1 which later ran clean unchanged.)
// R6 (8-wave split, redundant MFMA) REGRESSED to 405 us: lockstep
// barrier waves contend instead of covering latency (m190); reverted.
// R5b accounting: step = 1130 cyc; epilogue trans issue ~384 cyc
// (24 trans x ~16cyc wave64 quarter-rate) ~= measured VALUBusy 446.
// LDS read/write phase math shows both are phase-minimal (the 6.29M
// "conflict" counter counts inherent b128 multi-phase). -> lever is
// trans COUNT:
//   h' = (1-z)n + z*h  with z=1/(1+Z), n=(U-1)/(U+1), Z=e^-preZ,
//   U=e^{2(xn+r*hn)}  ==>  h' = [U*(Z+h) + (h-Z)] / [(U+1)*(Z+1)]
// merges the z-rcp and tanh-rcp into ONE rcp -> 5 trans/h (was 6).
// 2log2e prefolded into n-gate weights+biases kills the per-h mul.
// H-MFMAs reordered (R,Z,N)xhb0 then (R,Z,N)xhb1 for latency cover.
// Carries R5b's compiler-proof load pipeline: untracked inline-asm
// global_load_dwordx4 bursts, data-dep vmcnt(0) drains, raw
// lgkmcnt(0)+s_barrier (no vmcnt drain at barriers).
// __launch_bounds__(256,1): occupancy is structurally 1 wave/SIMD
// (256 batch-tiles x 4 waves = 1024 waves = exactly fills 256 CUs).

#define TSTEPS 512
#define IDIM 32
#define HDIM 64

typedef __bf16 bf16x8 __attribute__((ext_vector_type(8)));
typedef __bf16 bf16x4 __attribute__((ext_vector_type(4)));
typedef float f32x4 __attribute__((ext_vector_type(4)));

#define NLOG2E -1.4426950408889634f
#define TWOLOG2E 2.8853900817779268f

// Two untracked 16B loads (one timestep slice per lane = 8 floats =
// 2x float4) from base+literal offsets.
#define LOADPAIR(dst0, dst1, ptr, off)                                     \
    asm volatile("global_load_dwordx4 %0, %2, off offset:%c3\n\t"          \
                 "global_load_dwordx4 %1, %2, off offset:%c4"              \
        : "=&v"(dst0), "=&v"(dst1)                                         \
        : "v"(ptr), "i"(off), "i"((off) + 16));

// Issue one 8-timestep chunk (1 KiB contiguous per lane) as 16 untracked
// global_load_dwordx4. Stride between timesteps = IDIM*4 = 128 B.
#define ISSUE_CHUNK(qq, baseT) do {                                        \
    const float* _p = seqRow + (size_t)(baseT) * IDIM;                     \
    LOADPAIR(qq[0][0], qq[0][1], _p, 0)                                    \
    LOADPAIR(qq[1][0], qq[1][1], _p, 128)                                  \
    LOADPAIR(qq[2][0], qq[2][1], _p, 256)                                  \
    LOADPAIR(qq[3][0], qq[3][1], _p, 384)                                  \
    LOADPAIR(qq[4][0], qq[4][1], _p, 512)                                  \
    LOADPAIR(qq[5][0], qq[5][1], _p, 640)                                  \
    LOADPAIR(qq[6][0], qq[6][1], _p, 768)                                  \
    LOADPAIR(qq[7][0], qq[7][1], _p, 896)                                  \
} while (0)

// Drain the untracked loads; tie all destinations so no consumer can be
// scheduled above the wait (true data dependence).
#define WAITDEP(qq)                                                        \
    asm volatile("s_waitcnt vmcnt(0)"                                      \
        : "+v"(qq[0][0]), "+v"(qq[0][1]), "+v"(qq[1][0]), "+v"(qq[1][1]), \
          "+v"(qq[2][0]), "+v"(qq[2][1]), "+v"(qq[3][0]), "+v"(qq[3][1]), \
          "+v"(qq[4][0]), "+v"(qq[4][1]), "+v"(qq[5][0]), "+v"(qq[5][1]), \
          "+v"(qq[6][0]), "+v"(qq[6][1]), "+v"(qq[7][0]), "+v"(qq[7][1]))

// Raw barrier: LDS drained manually; NO vmcnt drain (the whole point).
// "memory" clobber pins DS ops (esp. the hOut ds_write) on the correct
// side of the barrier.
#define WG_BARRIER() do {                                                  \
    asm volatile("s_waitcnt lgkmcnt(0)" ::: "memory");                     \
    __builtin_amdgcn_s_barrier();                                          \
} while (0)

__global__ __launch_bounds__(256, 1) void gru_fused_kernel(
    const float* __restrict__ seq, const float* __restrict__ W_ih,
    const float* __restrict__ W_hh, const float* __restrict__ b_ih,
    const float* __restrict__ b_hh, float* __restrict__ out)
{
    __shared__ __bf16 hB[2][16][72];  // h^T double-buffered; 144 B row stride

    const int tid  = threadIdx.x;
    const int w    = tid >> 6;
    const int lane = tid & 63;
    const int l    = lane & 15;       // batch col
    const int q    = lane >> 4;       // quad
    const int b0   = blockIdx.x * 16;

    for (int i = tid; i < 2 * 16 * 72; i += 256)
        (&hB[0][0][0])[i] = (__bf16)0.0f;

    // ---- A-fragments; r,z gates pre-scaled by -log2e; n gate by 2log2e ----
    bf16x8 aH[3][2], aI[3];
    #pragma unroll
    for (int g = 0; g < 3; ++g) {
        const float scl = (g < 2) ? NLOG2E : TWOLOG2E;
        const int row = g * 64 + w * 16 + l;
        #pragma unroll
        for (int kc = 0; kc < 2; ++kc) {
            const float* p = W_hh + row * HDIM + kc * 32 + q * 8;
            #pragma unroll
            for (int j = 0; j < 8; ++j) aH[g][kc][j] = (__bf16)(scl * p[j]);
        }
        const float* pi = W_ih + row * IDIM + q * 8;
        #pragma unroll
        for (int j = 0; j < 8; ++j) aI[g][j] = (__bf16)(scl * pi[j]);
    }

    // ---- bias C-init vectors at this lane's C/D rows (hidden = w*16+4q+r) ----
    f32x4 biasR4, biasZ4, biasXN4, biasHN4;
    #pragma unroll
    for (int r = 0; r < 4; ++r) {
        const int g = w * 16 + 4 * q + r;
        biasR4[r]  = NLOG2E * (b_ih[g]      + b_hh[g]);
        biasZ4[r]  = NLOG2E * (b_ih[64 + g] + b_hh[64 + g]);
        biasXN4[r] = TWOLOG2E * b_ih[128 + g];
        biasHN4[r] = TWOLOG2E * b_hh[128 + g];
    }

    float h[4] = {0.f, 0.f, 0.f, 0.f};

    const float* seqRow = seq + ((size_t)(b0 + l) * TSTEPS) * IDIM + q * 8;

    // ---- 8-step register queues, loaded ONLY via untracked asm loads.
    // qA holds the even chunk (steps tc..tc+7), qB the odd (tc+8..tc+15).
    f32x4 qA[8][2], qB[8][2];
    ISSUE_CHUNK(qA, 0);
    ISSUE_CHUNK(qB, 8);
    WAITDEP(qA);            // vmcnt(0): one-time drain of both chunks
    WAITDEP(qB);            // free (already 0); establishes qB data-dep

    WG_BARRIER();           // hB zero-init visible

    // ---- t=0 x-part (bias-init C) ----
    bf16x8 xb;
    #pragma unroll
    for (int j = 0; j < 4; ++j) {
        xb[j]     = (__bf16)qA[0][0][j];
        xb[4 + j] = (__bf16)qA[0][1][j];
    }
    f32x4 accR  = __builtin_amdgcn_mfma_f32_16x16x32_bf16(aI[0], xb, biasR4, 0, 0, 0);
    f32x4 accZ  = __builtin_amdgcn_mfma_f32_16x16x32_bf16(aI[1], xb, biasZ4, 0, 0, 0);
    f32x4 accXN = __builtin_amdgcn_mfma_f32_16x16x32_bf16(aI[2], xb, biasXN4, 0, 0, 0);

    for (int tc = 0; tc < TSTEPS; tc += 16) {
        #pragma unroll
        for (int s = 0; s < 16; ++s) {
            const int buf = s & 1;  // tc is a multiple of 16

            // post-barrier critical path: h^T fragments
            bf16x8 hb0 = *(const bf16x8*)&hB[buf][l][q * 8];
            bf16x8 hb1 = *(const bf16x8*)&hB[buf][l][32 + q * 8];

            // hb0 group first, then hb1 group: independent chains cover
            // each other's MFMA latency.
            accR = __builtin_amdgcn_mfma_f32_16x16x32_bf16(aH[0][0], hb0, accR, 0, 0, 0);
            accZ = __builtin_amdgcn_mfma_f32_16x16x32_bf16(aH[1][0], hb0, accZ, 0, 0, 0);
            f32x4 accHN = __builtin_amdgcn_mfma_f32_16x16x32_bf16(aH[2][0], hb0, biasHN4, 0, 0, 0);
            accR = __builtin_amdgcn_mfma_f32_16x16x32_bf16(aH[0][1], hb1, accR, 0, 0, 0);
            accZ = __builtin_amdgcn_mfma_f32_16x16x32_bf16(aH[1][1], hb1, accZ, 0, 0, 0);
            accHN = __builtin_amdgcn_mfma_f32_16x16x32_bf16(aH[2][1], hb1, accHN, 0, 0, 0);

            bf16x4 hOut;
            #pragma unroll
            for (int r = 0; r < 4; ++r) {
                // R = e^-preR, Z = e^-preZ (r,z prescaled by -log2e);
                // U = e^{2(xn + rg*hn)} (n-gate prescaled by 2log2e).
                // h' = [U*(Z+h) + (h-Z)] / [(U+1)*(Z+1)]  — one rcp for
                // z-gate + tanh combined. 5 trans/h (was 6).
                const float R  = __builtin_amdgcn_exp2f(accR[r]);
                const float rg = __builtin_amdgcn_rcpf(R + 1.0f);
                const float v2 = __builtin_fmaf(rg, accHN[r], accXN[r]);
                const float U  = __builtin_amdgcn_exp2f(v2);
                const float Z  = __builtin_amdgcn_exp2f(accZ[r]);
                const float num = __builtin_fmaf(U, Z + h[r], h[r] - Z);
                const float den = (U + 1.0f) * (Z + 1.0f);
                h[r] = num * __builtin_amdgcn_rcpf(den);
                hOut[r] = (__bf16)h[r];
            }
            *(bf16x4*)&hB[buf ^ 1][l][w * 16 + 4 * q] = hOut;

            // burst pipeline: drain the chunk first needed THIS step (issued
            // 8 steps ago, ~2500+ cyc of cover), then issue the next chunk.
            // All other barriers see zero outstanding vmem.
            if (s == 7) {
                WAITDEP(qB);                              // chunk tc+8 ready
                if (tc + 16 < TSTEPS) ISSUE_CHUNK(qA, tc + 16);
            }
            if (s == 15) {
                WAITDEP(qA);                              // chunk tc+16 ready
                if (tc + 24 < TSTEPS) ISSUE_CHUNK(qB, tc + 24);
            }

            // ---- pre-barrier work for t+1 (h-independent): cvt + x-proj MFMAs ----
            // s+1: slot (s+1)&7 of qA if (s+1)<8 else qB; at s==15 uses qA[0]
            // (refilled with chunk tc+16 at s==7, drained just above). Final
            // step computes a dead x-proj for t=512 from stale regs — harmless.
            {
                const int s1 = s + 1;
                const f32x4* x0 = (s1 < 8) ? &qA[s1 & 7][0]
                                           : (s1 < 16) ? &qB[s1 & 7][0]
                                                       : &qA[0][0];
                bf16x8 xb1;
                #pragma unroll
                for (int j = 0; j < 4; ++j) {
                    xb1[j]     = (__bf16)x0[0][j];
                    xb1[4 + j] = (__bf16)x0[1][j];
                }
                accR  = __builtin_amdgcn_mfma_f32_16x16x32_bf16(aI[0], xb1, biasR4, 0, 0, 0);
                accZ  = __builtin_amdgcn_mfma_f32_16x16x32_bf16(aI[1], xb1, biasZ4, 0, 0, 0);
                accXN = __builtin_amdgcn_mfma_f32_16x16x32_bf16(aI[2], xb1, biasXN4, 0, 0, 0);
            }

            WG_BARRIER();
        }
    }

    float4 o = {h[0], h[1], h[2], h[3]};
    *(float4*)&out[(size_t)(b0 + l) * HDIM + w * 16 + 4 * q] = o;
}

extern "C" void kernel_launch(void* const* d_in, const int* in_sizes, int n_in,
                              void* d_out, int out_size, void* d_ws, size_t ws_size,
                              hipStream_t stream) {
    const float* seq  = (const float*)d_in[0];
    const float* W_ih = (const float*)d_in[1];
    const float* W_hh = (const float*)d_in[2];
    const float* b_ih = (const float*)d_in[3];
    const float* b_hh = (const float*)d_in[4];
    float* out = (float*)d_out;
    gru_fused_kernel<<<256, 256, 0, stream>>>(seq, W_ih, W_hh, b_ih, b_hh, out);
}

// Round 9
// 482.660 us; speedup vs baseline: 1.3291x; 1.0046x over previous
//
#include <hip/hip_runtime.h>

// GRU: B=4096, T=512, I=32, H=64. One WG per 16-batch tile, 4 waves.
// Wave w owns hidden slice [w*16, w*16+16) for all 3 gates.
// hp^T = W_hh * h^T: A = weight rows in registers, B = h^T from LDS.
//
// R8 = R7 (237 us) + step restructure for latency cover. (Round 8:
// verbatim resubmit — Round 7 proposal hit GPUAcquisitionTimeout,
// kernel never ran.)
// R7 post-mortem: removing 4 trans/step gained only 1.7% -> step is NOT
// trans-issue-bound; ~550 cyc/step is exposed latency (ds_read ~120
// with nothing to overlap, dep chains, barrier tail inflated by the
// pre-barrier x-proj block). Changes:
//  1. x-proj moved POST-barrier, between ds_read issue and H-MFMAs:
//     8 cvts + 3 MFMAs (~55 cyc) execute under the ds_read latency
//     instead of delaying barrier arrival. acc no longer loop-carried;
//     t=0 prologue and dead last-step x-proj eliminated.
//  2. epilogue non-trans arithmetic in f32x2 (v_pk_add/mul/fma_f32):
//     ~18 scalar -> ~9 packed ops per step (~36 cyc saved).
// Numerics identical to R7 (same merged-rcp formula; absmax 0.0039).
// Carries R5b's compiler-proof load pipeline: untracked inline-asm
// global_load_dwordx4 bursts, data-dep vmcnt(0) drains, raw
// lgkmcnt(0)+s_barrier (no vmcnt drain at barriers).
// __launch_bounds__(256,1): occupancy is structurally 1 wave/SIMD
// (256 batch-tiles x 4 waves = 1024 waves = exactly fills 256 CUs).

#define TSTEPS 512
#define IDIM 32
#define HDIM 64

typedef __bf16 bf16x8 __attribute__((ext_vector_type(8)));
typedef __bf16 bf16x4 __attribute__((ext_vector_type(4)));
typedef float f32x4 __attribute__((ext_vector_type(4)));
typedef float f32x2 __attribute__((ext_vector_type(2)));

#define NLOG2E -1.4426950408889634f
#define TWOLOG2E 2.8853900817779268f

// Two untracked 16B loads (one timestep slice per lane = 8 floats =
// 2x float4) from base+literal offsets.
#define LOADPAIR(dst0, dst1, ptr, off)                                     \
    asm volatile("global_load_dwordx4 %0, %2, off offset:%c3\n\t"          \
                 "global_load_dwordx4 %1, %2, off offset:%c4"              \
        : "=&v"(dst0), "=&v"(dst1)                                         \
        : "v"(ptr), "i"(off), "i"((off) + 16));

// Issue one 8-timestep chunk (1 KiB contiguous per lane) as 16 untracked
// global_load_dwordx4. Stride between timesteps = IDIM*4 = 128 B.
#define ISSUE_CHUNK(qq, baseT) do {                                        \
    const float* _p = seqRow + (size_t)(baseT) * IDIM;                     \
    LOADPAIR(qq[0][0], qq[0][1], _p, 0)                                    \
    LOADPAIR(qq[1][0], qq[1][1], _p, 128)                                  \
    LOADPAIR(qq[2][0], qq[2][1], _p, 256)                                  \
    LOADPAIR(qq[3][0], qq[3][1], _p, 384)                                  \
    LOADPAIR(qq[4][0], qq[4][1], _p, 512)                                  \
    LOADPAIR(qq[5][0], qq[5][1], _p, 640)                                  \
    LOADPAIR(qq[6][0], qq[6][1], _p, 768)                                  \
    LOADPAIR(qq[7][0], qq[7][1], _p, 896)                                  \
} while (0)

// Drain the untracked loads; tie all destinations so no consumer can be
// scheduled above the wait (true data dependence).
#define WAITDEP(qq)                                                        \
    asm volatile("s_waitcnt vmcnt(0)"                                      \
        : "+v"(qq[0][0]), "+v"(qq[0][1]), "+v"(qq[1][0]), "+v"(qq[1][1]), \
          "+v"(qq[2][0]), "+v"(qq[2][1]), "+v"(qq[3][0]), "+v"(qq[3][1]), \
          "+v"(qq[4][0]), "+v"(qq[4][1]), "+v"(qq[5][0]), "+v"(qq[5][1]), \
          "+v"(qq[6][0]), "+v"(qq[6][1]), "+v"(qq[7][0]), "+v"(qq[7][1]))

// Raw barrier: LDS drained manually; NO vmcnt drain (the whole point).
// "memory" clobber pins DS ops (esp. the hOut ds_write) on the correct
// side of the barrier.
#define WG_BARRIER() do {                                                  \
    asm volatile("s_waitcnt lgkmcnt(0)" ::: "memory");                     \
    __builtin_amdgcn_s_barrier();                                          \
} while (0)

__global__ __launch_bounds__(256, 1) void gru_fused_kernel(
    const float* __restrict__ seq, const float* __restrict__ W_ih,
    const float* __restrict__ W_hh, const float* __restrict__ b_ih,
    const float* __restrict__ b_hh, float* __restrict__ out)
{
    __shared__ __bf16 hB[2][16][72];  // h^T double-buffered; 144 B row stride

    const int tid  = threadIdx.x;
    const int w    = tid >> 6;
    const int lane = tid & 63;
    const int l    = lane & 15;       // batch col
    const int q    = lane >> 4;       // quad
    const int b0   = blockIdx.x * 16;

    for (int i = tid; i < 2 * 16 * 72; i += 256)
        (&hB[0][0][0])[i] = (__bf16)0.0f;

    // ---- A-fragments; r,z gates pre-scaled by -log2e; n gate by 2log2e ----
    bf16x8 aH[3][2], aI[3];
    #pragma unroll
    for (int g = 0; g < 3; ++g) {
        const float scl = (g < 2) ? NLOG2E : TWOLOG2E;
        const int row = g * 64 + w * 16 + l;
        #pragma unroll
        for (int kc = 0; kc < 2; ++kc) {
            const float* p = W_hh + row * HDIM + kc * 32 + q * 8;
            #pragma unroll
            for (int j = 0; j < 8; ++j) aH[g][kc][j] = (__bf16)(scl * p[j]);
        }
        const float* pi = W_ih + row * IDIM + q * 8;
        #pragma unroll
        for (int j = 0; j < 8; ++j) aI[g][j] = (__bf16)(scl * pi[j]);
    }

    // ---- bias C-init vectors at this lane's C/D rows (hidden = w*16+4q+r) ----
    f32x4 biasR4, biasZ4, biasXN4, biasHN4;
    #pragma unroll
    for (int r = 0; r < 4; ++r) {
        const int g = w * 16 + 4 * q + r;
        biasR4[r]  = NLOG2E * (b_ih[g]      + b_hh[g]);
        biasZ4[r]  = NLOG2E * (b_ih[64 + g] + b_hh[64 + g]);
        biasXN4[r] = TWOLOG2E * b_ih[128 + g];
        biasHN4[r] = TWOLOG2E * b_hh[128 + g];
    }

    float h[4] = {0.f, 0.f, 0.f, 0.f};

    const float* seqRow = seq + ((size_t)(b0 + l) * TSTEPS) * IDIM + q * 8;

    // ---- 8-step register queues, loaded ONLY via untracked asm loads.
    // qA holds the even chunk (steps tc..tc+7), qB the odd (tc+8..tc+15).
    f32x4 qA[8][2], qB[8][2];
    ISSUE_CHUNK(qA, 0);
    ISSUE_CHUNK(qB, 8);
    WAITDEP(qA);            // vmcnt(0): one-time drain of both chunks
    WAITDEP(qB);            // free (already 0); establishes qB data-dep

    WG_BARRIER();           // hB zero-init visible

    for (int tc = 0; tc < TSTEPS; tc += 16) {
        #pragma unroll
        for (int s = 0; s < 16; ++s) {
            const int buf = s & 1;  // tc is a multiple of 16

            // post-barrier: issue h^T fragment reads first...
            bf16x8 hb0 = *(const bf16x8*)&hB[buf][l][q * 8];
            bf16x8 hb1 = *(const bf16x8*)&hB[buf][l][32 + q * 8];

            // ...then x-proj for THIS step (h-independent: cvt + 3 MFMAs
            // execute under the ds_read latency).
            const f32x4* x0 = (s < 8) ? &qA[s & 7][0] : &qB[s & 7][0];
            bf16x8 xb;
            #pragma unroll
            for (int j = 0; j < 4; ++j) {
                xb[j]     = (__bf16)x0[0][j];
                xb[4 + j] = (__bf16)x0[1][j];
            }
            f32x4 accR  = __builtin_amdgcn_mfma_f32_16x16x32_bf16(aI[0], xb, biasR4, 0, 0, 0);
            f32x4 accZ  = __builtin_amdgcn_mfma_f32_16x16x32_bf16(aI[1], xb, biasZ4, 0, 0, 0);
            f32x4 accXN = __builtin_amdgcn_mfma_f32_16x16x32_bf16(aI[2], xb, biasXN4, 0, 0, 0);

            // H part: hb0 group then hb1 group (chains cover each other).
            accR = __builtin_amdgcn_mfma_f32_16x16x32_bf16(aH[0][0], hb0, accR, 0, 0, 0);
            accZ = __builtin_amdgcn_mfma_f32_16x16x32_bf16(aH[1][0], hb0, accZ, 0, 0, 0);
            f32x4 accHN = __builtin_amdgcn_mfma_f32_16x16x32_bf16(aH[2][0], hb0, biasHN4, 0, 0, 0);
            accR = __builtin_amdgcn_mfma_f32_16x16x32_bf16(aH[0][1], hb1, accR, 0, 0, 0);
            accZ = __builtin_amdgcn_mfma_f32_16x16x32_bf16(aH[1][1], hb1, accZ, 0, 0, 0);
            accHN = __builtin_amdgcn_mfma_f32_16x16x32_bf16(aH[2][1], hb1, accHN, 0, 0, 0);

            // epilogue: merged-rcp formula, non-trans math in f32x2
            // (v_pk_add/mul/fma_f32). Pairs (0,1) and (2,3); all indices
            // compile-time (rule #20).
            bf16x4 hOut;
            #pragma unroll
            for (int p = 0; p < 2; ++p) {
                f32x2 eR, eZ, hn, xn, hh;
                eR[0] = __builtin_amdgcn_exp2f(accR[2*p]);
                eR[1] = __builtin_amdgcn_exp2f(accR[2*p + 1]);
                eZ[0] = __builtin_amdgcn_exp2f(accZ[2*p]);
                eZ[1] = __builtin_amdgcn_exp2f(accZ[2*p + 1]);
                hn[0] = accHN[2*p]; hn[1] = accHN[2*p + 1];
                xn[0] = accXN[2*p]; xn[1] = accXN[2*p + 1];
                hh[0] = h[2*p];     hh[1] = h[2*p + 1];
                const f32x2 eR1 = eR + 1.0f;                 // pk_add
                f32x2 rg;
                rg[0] = __builtin_amdgcn_rcpf(eR1[0]);
                rg[1] = __builtin_amdgcn_rcpf(eR1[1]);
                const f32x2 v2 = rg * hn + xn;               // pk_fma
                f32x2 U;
                U[0] = __builtin_amdgcn_exp2f(v2[0]);
                U[1] = __builtin_amdgcn_exp2f(v2[1]);
                const f32x2 num = U * (eZ + hh) + (hh - eZ); // pk_add/sub/fma
                const f32x2 den = (U + 1.0f) * (eZ + 1.0f);  // pk_add x2, pk_mul
                f32x2 rd;
                rd[0] = __builtin_amdgcn_rcpf(den[0]);
                rd[1] = __builtin_amdgcn_rcpf(den[1]);
                const f32x2 hN = num * rd;                   // pk_mul
                h[2*p]     = hN[0];
                h[2*p + 1] = hN[1];
                hOut[2*p]     = (__bf16)hN[0];
                hOut[2*p + 1] = (__bf16)hN[1];
            }
            *(bf16x4*)&hB[buf ^ 1][l][w * 16 + 4 * q] = hOut;

            // burst pipeline: drain the chunk first needed NEXT step
            // (issued 8+ steps ago), then issue the next chunk.
            // All other barriers see zero outstanding vmem.
            if (s == 7) {
                WAITDEP(qB);                              // chunk tc+8 ready
                if (tc + 16 < TSTEPS) ISSUE_CHUNK(qA, tc + 16);
            }
            if (s == 15) {
                WAITDEP(qA);                              // chunk tc+16 ready
                if (tc + 24 < TSTEPS) ISSUE_CHUNK(qB, tc + 24);
            }

            WG_BARRIER();
        }
    }

    float4 o = {h[0], h[1], h[2], h[3]};
    *(float4*)&out[(size_t)(b0 + l) * HDIM + w * 16 + 4 * q] = o;
}

extern "C" void kernel_launch(void* const* d_in, const int* in_sizes, int n_in,
                              void* d_out, int out_size, void* d_ws, size_t ws_size,
                              hipStream_t stream) {
    const float* seq  = (const float*)d_in[0];
    const float* W_ih = (const float*)d_in[1];
    const float* W_hh = (const float*)d_in[2];
    const float* b_ih = (const float*)d_in[3];
    const float* b_hh = (const float*)d_in[4];
    float* out = (float*)d_out;
    gru_fused_kernel<<<256, 256, 0, stream>>>(seq, W_ih, W_hh, b_ih, b_hh, out);
}